// Round 1
// baseline (526.180 us; speedup 1.0000x reference)
//
#include <hip/hip_runtime.h>

// Problem constants (B=2, N=1000, D=6, L=12, C=32, K=16, H=8)
#define NB 2
#define NN 1000
#define ND 6
#define NK 16
#define NH 8
#define DM 384        // L*C
#define MROWS 12000   // B*N*D
#define NTOK 2000     // B*N
#define NS 96         // K*D

static __device__ __forceinline__ float4 ld4(const float* p){ return *reinterpret_cast<const float4*>(p); }
static __device__ __forceinline__ void st4(float* p, float4 v){ *reinterpret_cast<float4*>(p) = v; }

#define SCALE 0.14433756729740646f   // 1/sqrt(48)
#define GELU_K 0.70710678118654752f  // 1/sqrt(2)

// ---------------------------------------------------------------------------
// Kernel 1: Qa/Ka/Va = x @ {Wq,Wk,Wv} + bias.   M=12000, N=384 (x3), K=384.
// 128x128 tile, BK=16, 256 threads, 8x8 micro-tile.
// ---------------------------------------------------------------------------
__global__ __launch_bounds__(256, 2)
void k_qkv(const float* __restrict__ x,
           const float* __restrict__ Wq, const float* __restrict__ bq,
           const float* __restrict__ Wk, const float* __restrict__ bk,
           const float* __restrict__ Wv, const float* __restrict__ bv,
           float* __restrict__ Qa, float* __restrict__ Ka, float* __restrict__ Va)
{
    __shared__ float As[16*132];   // transposed A tile [k][row], pad 132 -> 2-way max
    __shared__ float Bs[16*128];   // B tile [k][col]

    const int tid = threadIdx.x;
    const int tx = tid & 15, ty = tid >> 4;
    const int r0 = blockIdx.x * 128;
    const int wsel = blockIdx.y / 3;
    const int c0 = (blockIdx.y % 3) * 128;
    const float* W   = (wsel == 0) ? Wq : (wsel == 1) ? Wk : Wv;
    const float* bi  = (wsel == 0) ? bq : (wsel == 1) ? bk : bv;
    float*       out = (wsel == 0) ? Qa : (wsel == 1) ? Ka : Va;

    float acc[8][8];
    #pragma unroll
    for (int i = 0; i < 8; i++)
        #pragma unroll
        for (int j = 0; j < 8; j++) acc[i][j] = 0.f;

    const int lrow = tid >> 2;          // 0..63
    const int lkc  = (tid & 3) << 2;    // 0,4,8,12
    const int bkr  = tid >> 5;          // 0..7
    const int bcc  = (tid & 31) << 2;   // 0..124

    for (int k0 = 0; k0 < DM; k0 += 16) {
        #pragma unroll
        for (int hf = 0; hf < 2; hf++) {
            const int r = lrow + hf*64;
            const int gr = r0 + r;
            float4 v = make_float4(0.f, 0.f, 0.f, 0.f);
            if (gr < MROWS) v = ld4(&x[(size_t)gr*DM + k0 + lkc]);
            As[(lkc+0)*132 + r] = v.x;
            As[(lkc+1)*132 + r] = v.y;
            As[(lkc+2)*132 + r] = v.z;
            As[(lkc+3)*132 + r] = v.w;
        }
        #pragma unroll
        for (int hf = 0; hf < 2; hf++) {
            const int kr = bkr + hf*8;
            st4(&Bs[kr*128 + bcc], ld4(&W[(size_t)(k0+kr)*DM + c0 + bcc]));
        }
        __syncthreads();
        #pragma unroll
        for (int kk = 0; kk < 16; kk++) {
            const float4 a0 = ld4(&As[kk*132 + 4*ty]);
            const float4 a1 = ld4(&As[kk*132 + 64 + 4*ty]);
            const float4 b0 = ld4(&Bs[kk*128 + 4*tx]);
            const float4 b1 = ld4(&Bs[kk*128 + 64 + 4*tx]);
            const float a[8] = {a0.x,a0.y,a0.z,a0.w,a1.x,a1.y,a1.z,a1.w};
            const float b[8] = {b0.x,b0.y,b0.z,b0.w,b1.x,b1.y,b1.z,b1.w};
            #pragma unroll
            for (int i = 0; i < 8; i++)
                #pragma unroll
                for (int j = 0; j < 8; j++)
                    acc[i][j] = fmaf(a[i], b[j], acc[i][j]);
        }
        __syncthreads();
    }

    #pragma unroll
    for (int i = 0; i < 8; i++) {
        const int r = (i < 4) ? (4*ty + i) : (64 + 4*ty + i - 4);
        const int gr = r0 + r;
        if (gr >= MROWS) continue;
        #pragma unroll
        for (int jh = 0; jh < 2; jh++) {
            const int cl = jh ? (64 + 4*tx) : (4*tx);
            const int c = c0 + cl;
            const float4 bv = ld4(&bi[c]);
            float4 v;
            v.x = acc[i][4*jh+0] + bv.x;
            v.y = acc[i][4*jh+1] + bv.y;
            v.z = acc[i][4*jh+2] + bv.z;
            v.w = acc[i][4*jh+3] + bv.w;
            st4(&out[(size_t)gr*DM + c], v);
        }
    }
}

// ---------------------------------------------------------------------------
// Kernel 2: attention per token (block), heads looped. ctx overwrites Qa.
// K/V head-slices staged in LDS, row pitch 52 floats => b128 reads tile banks.
// ---------------------------------------------------------------------------
__global__ __launch_bounds__(256, 2)
void k_attn(float* __restrict__ Qa,           // in: Q rows; out: ctx (in-place)
            const float* __restrict__ Ka,
            const float* __restrict__ Va,
            const int* __restrict__ topk)
{
    __shared__ float Ks[NS*52];
    __shared__ float Vs[NS*52];
    __shared__ float Qs[6*48];
    __shared__ float Sm[6*96];
    __shared__ int   idxs[NK];

    const int tid = threadIdx.x;
    const int bn  = blockIdx.x;                  // 0..1999
    const int bb  = (bn >= NN) ? NN : 0;         // b*1000
    const size_t qbase = (size_t)bn * ND * DM;

    if (tid < NK) idxs[tid] = topk[bn*NK + tid];
    __syncthreads();

    for (int h = 0; h < NH; ++h) {
        // ---- stage Q head-slice: 6 x 48 (72 float4)
        if (tid < 72) {
            const int l = tid / 12, j = tid % 12;
            st4(&Qs[l*48 + 4*j], ld4(&Qa[qbase + (size_t)l*DM + h*48 + 4*j]));
        }
        // ---- stage gathered K/V head-slices: 96 x 48 each (1152 float4 each)
        for (int p4 = tid; p4 < 1152; p4 += 256) {
            const int s = p4 / 12;
            const int j = p4 - s*12;
            const int k = s / 6;
            const int d = s - k*6;
            const size_t src = ((size_t)(bb + idxs[k])*ND + d)*DM + h*48 + 4*j;
            st4(&Ks[s*52 + 4*j], ld4(&Ka[src]));
            st4(&Vs[s*52 + 4*j], ld4(&Va[src]));
        }
        __syncthreads();

        // ---- scores: thread (s, g) computes 3 rows' dot with K row s
        if (tid < 192) {
            const int s  = tid % 96;
            const int l0 = (tid / 96) * 3;
            float a0 = 0.f, a1 = 0.f, a2 = 0.f;
            #pragma unroll
            for (int j = 0; j < 12; j++) {
                const float4 kv = ld4(&Ks[s*52 + 4*j]);
                const float4 q0 = ld4(&Qs[(l0+0)*48 + 4*j]);
                const float4 q1 = ld4(&Qs[(l0+1)*48 + 4*j]);
                const float4 q2 = ld4(&Qs[(l0+2)*48 + 4*j]);
                a0 = fmaf(kv.x,q0.x, fmaf(kv.y,q0.y, fmaf(kv.z,q0.z, fmaf(kv.w,q0.w, a0))));
                a1 = fmaf(kv.x,q1.x, fmaf(kv.y,q1.y, fmaf(kv.z,q1.z, fmaf(kv.w,q1.w, a1))));
                a2 = fmaf(kv.x,q2.x, fmaf(kv.y,q2.y, fmaf(kv.z,q2.z, fmaf(kv.w,q2.w, a2))));
            }
            Sm[(l0+0)*96 + s] = a0 * SCALE;
            Sm[(l0+1)*96 + s] = a1 * SCALE;
            Sm[(l0+2)*96 + s] = a2 * SCALE;
        }
        __syncthreads();

        // ---- softmax over s (96): wave w owns rows {w, w+4}
        {
            const int w = tid >> 6, lane = tid & 63;
            for (int l = w; l < 6; l += 4) {
                const float v0 = Sm[l*96 + lane];
                const float v1 = (lane < 32) ? Sm[l*96 + 64 + lane] : -3.0e38f;
                float m = fmaxf(v0, v1);
                #pragma unroll
                for (int off = 32; off; off >>= 1) m = fmaxf(m, __shfl_xor(m, off));
                const float e0 = expf(v0 - m);
                const float e1 = (lane < 32) ? expf(v1 - m) : 0.f;
                float sum = e0 + e1;
                #pragma unroll
                for (int off = 32; off; off >>= 1) sum += __shfl_xor(sum, off);
                const float inv = 1.f / sum;
                Sm[l*96 + lane] = e0 * inv;
                if (lane < 32) Sm[l*96 + 64 + lane] = e1 * inv;
            }
        }
        __syncthreads();

        // ---- ctx = A @ V : thread (l, j) owns float4 of output row l
        if (tid < 72) {
            const int l = tid / 12, j = tid % 12;
            float4 acc = make_float4(0.f, 0.f, 0.f, 0.f);
            #pragma unroll 4
            for (int s = 0; s < 96; s++) {
                const float a = Sm[l*96 + s];
                const float4 v = ld4(&Vs[s*52 + 4*j]);
                acc.x = fmaf(a, v.x, acc.x);
                acc.y = fmaf(a, v.y, acc.y);
                acc.z = fmaf(a, v.z, acc.z);
                acc.w = fmaf(a, v.w, acc.w);
            }
            st4(&Qa[qbase + (size_t)l*DM + h*48 + 4*j], acc);   // overwrite Q slice h
        }
        __syncthreads();
    }
}

// ---------------------------------------------------------------------------
// Kernel 3: out = LN(x + ctx@Wo + bo); out += MLP(out).  Fully fused.
// GEMM: 64x128 tile, BK=16, 4x8 micro. Then per-thread one 32-wide LN group.
// ---------------------------------------------------------------------------
__global__ __launch_bounds__(256, 2)
void k_out(const float* __restrict__ ctx, const float* __restrict__ x,
           const float* __restrict__ Wo, const float* __restrict__ bo,
           const float* __restrict__ ln_g, const float* __restrict__ ln_b,
           const float* __restrict__ W1, const float* __restrict__ b1,
           const float* __restrict__ W2, const float* __restrict__ b2,
           float* __restrict__ out)
{
    __shared__ float smem[8256];   // GEMM: As[16*68]@0, Bs[16*128]@1088 ; then hs[64*129]
    __shared__ float W1s[2048];    // [c][o] row-major (32x64)
    __shared__ float W2t[2048];    // transposed: [c][o] (32x64)
    __shared__ float b1s[64];
    __shared__ float cns[96];      // ln_g | ln_b | b2

    const int tid = threadIdx.x;
    const int tx = tid & 15, ty = tid >> 4;
    const int r0 = blockIdx.x * 64;
    const int c0 = blockIdx.y * 128;

    for (int p = tid; p < 2048; p += 256) {
        W1s[p] = W1[p];
        const int o = p >> 5, c = p & 31;   // W2 is [o][c]
        W2t[c*64 + o] = W2[p];
    }
    if (tid < 64) b1s[tid] = b1[tid];
    if (tid < 32) { cns[tid] = ln_g[tid]; cns[32+tid] = ln_b[tid]; cns[64+tid] = b2[tid]; }

    float* As = smem;            // [16][68] transposed
    float* Bs = smem + 1088;     // [16][128]

    float acc[4][8];
    #pragma unroll
    for (int i = 0; i < 4; i++)
        #pragma unroll
        for (int j = 0; j < 8; j++) acc[i][j] = 0.f;

    const int lrow = tid >> 2;          // 0..63
    const int lkc  = (tid & 3) << 2;
    const int bkr  = tid >> 5;
    const int bcc  = (tid & 31) << 2;

    for (int k0 = 0; k0 < DM; k0 += 16) {
        {
            const int gr = r0 + lrow;
            float4 v = make_float4(0.f, 0.f, 0.f, 0.f);
            if (gr < MROWS) v = ld4(&ctx[(size_t)gr*DM + k0 + lkc]);
            As[(lkc+0)*68 + lrow] = v.x;
            As[(lkc+1)*68 + lrow] = v.y;
            As[(lkc+2)*68 + lrow] = v.z;
            As[(lkc+3)*68 + lrow] = v.w;
        }
        #pragma unroll
        for (int hf = 0; hf < 2; hf++) {
            const int kr = bkr + hf*8;
            st4(&Bs[kr*128 + bcc], ld4(&Wo[(size_t)(k0+kr)*DM + c0 + bcc]));
        }
        __syncthreads();
        #pragma unroll
        for (int kk = 0; kk < 16; kk++) {
            const float4 a0 = ld4(&As[kk*68 + 4*ty]);
            const float4 b0 = ld4(&Bs[kk*128 + 4*tx]);
            const float4 b1v = ld4(&Bs[kk*128 + 64 + 4*tx]);
            const float a[4] = {a0.x,a0.y,a0.z,a0.w};
            const float b[8] = {b0.x,b0.y,b0.z,b0.w,b1v.x,b1v.y,b1v.z,b1v.w};
            #pragma unroll
            for (int i = 0; i < 4; i++)
                #pragma unroll
                for (int j = 0; j < 8; j++)
                    acc[i][j] = fmaf(a[i], b[j], acc[i][j]);
        }
        __syncthreads();
    }

    // epilogue: h = ctx@Wo + bo + x  -> hs (aliases As/Bs; safe after last sync)
    float* hs = smem;   // [64][129]
    #pragma unroll
    for (int i = 0; i < 4; i++) {
        const int r = 4*ty + i;
        const int gr = r0 + r;
        if (gr < MROWS) {
            #pragma unroll
            for (int jh = 0; jh < 2; jh++) {
                const int cl = jh ? (64 + 4*tx) : (4*tx);
                const int c = c0 + cl;
                const float4 xv = ld4(&x[(size_t)gr*DM + c]);
                const float4 bv = ld4(&bo[c]);
                hs[r*129 + cl + 0] = acc[i][4*jh+0] + bv.x + xv.x;
                hs[r*129 + cl + 1] = acc[i][4*jh+1] + bv.y + xv.y;
                hs[r*129 + cl + 2] = acc[i][4*jh+2] + bv.z + xv.z;
                hs[r*129 + cl + 3] = acc[i][4*jh+3] + bv.w + xv.w;
            }
        }
    }
    __syncthreads();

    // LN + MLP: thread -> (row = tid&63, group g = tid>>6); group = 32 cols
    {
        const int row = tid & 63, g = tid >> 6;
        const int gr = r0 + row;
        if (gr < MROWS) {
            const float* hrow = &hs[row*129 + g*32];
            float mu = 0.f;
            #pragma unroll
            for (int c = 0; c < 32; c++) mu += hrow[c];
            mu *= 0.03125f;
            float var = 0.f;
            #pragma unroll
            for (int c = 0; c < 32; c++) { const float d = hrow[c] - mu; var = fmaf(d, d, var); }
            var *= 0.03125f;
            const float rstd = 1.0f / sqrtf(var + 1e-5f);

            // layer1: y = fused @ W1 + b1   (y statically indexed)
            float y[64];
            #pragma unroll
            for (int o4 = 0; o4 < 16; o4++) {
                const float4 bv = ld4(&b1s[4*o4]);
                y[4*o4+0] = bv.x; y[4*o4+1] = bv.y; y[4*o4+2] = bv.z; y[4*o4+3] = bv.w;
            }
            for (int c = 0; c < 32; c++) {
                const float fc = (hrow[c] - mu) * rstd * cns[c] + cns[32 + c];
                const float4* w = (const float4*)&W1s[c*64];
                #pragma unroll
                for (int j = 0; j < 16; j++) {
                    const float4 wv = w[j];
                    y[4*j+0] = fmaf(fc, wv.x, y[4*j+0]);
                    y[4*j+1] = fmaf(fc, wv.y, y[4*j+1]);
                    y[4*j+2] = fmaf(fc, wv.z, y[4*j+2]);
                    y[4*j+3] = fmaf(fc, wv.w, y[4*j+3]);
                }
            }
            // exact GELU
            #pragma unroll
            for (int o = 0; o < 64; o++) {
                const float v = y[o];
                y[o] = 0.5f * v * (1.0f + erff(v * GELU_K));
            }
            // layer2 + final add:  out = fused + (gelu(y) @ W2 + b2)
            float* orow = &out[(size_t)gr*DM + c0 + g*32];
            for (int c = 0; c < 32; c++) {
                const float fc = (hrow[c] - mu) * rstd * cns[c] + cns[32 + c];
                float zc = cns[64 + c];
                const float4* w = (const float4*)&W2t[c*64];
                #pragma unroll
                for (int j = 0; j < 16; j++) {
                    const float4 wv = w[j];
                    zc = fmaf(y[4*j+0], wv.x, zc);
                    zc = fmaf(y[4*j+1], wv.y, zc);
                    zc = fmaf(y[4*j+2], wv.z, zc);
                    zc = fmaf(y[4*j+3], wv.w, zc);
                }
                orow[c] = fc + zc;
            }
        }
    }
}

// ---------------------------------------------------------------------------
extern "C" void kernel_launch(void* const* d_in, const int* in_sizes, int n_in,
                              void* d_out, int out_size, void* d_ws, size_t ws_size,
                              hipStream_t stream)
{
    const float* x   = (const float*)d_in[0];
    const int*   tk  = (const int*)  d_in[1];
    const float* Wq  = (const float*)d_in[2];
    const float* bq  = (const float*)d_in[3];
    const float* Wk  = (const float*)d_in[4];
    const float* bk  = (const float*)d_in[5];
    const float* Wv  = (const float*)d_in[6];
    const float* bv  = (const float*)d_in[7];
    const float* Wo  = (const float*)d_in[8];
    const float* bo  = (const float*)d_in[9];
    const float* lng = (const float*)d_in[10];
    const float* lnb = (const float*)d_in[11];
    const float* W1  = (const float*)d_in[12];
    const float* b1  = (const float*)d_in[13];
    const float* W2  = (const float*)d_in[14];
    const float* b2  = (const float*)d_in[15];
    float* out = (float*)d_out;

    // workspace: Qa (becomes ctx in-place), Ka, Va  — 3 * 12000*384 floats = 55.3 MB
    float* Qa = (float*)d_ws;
    float* Ka = Qa + (size_t)MROWS * DM;
    float* Va = Ka + (size_t)MROWS * DM;

    k_qkv<<<dim3(94, 9), 256, 0, stream>>>(x, Wq, bq, Wk, bk, Wv, bv, Qa, Ka, Va);
    k_attn<<<dim3(NTOK), 256, 0, stream>>>(Qa, Ka, Va, tk);
    k_out<<<dim3(188, 3), 256, 0, stream>>>(Qa, x, Wo, bo, lng, lnb, W1, b1, W2, b2, out);
}

// Round 2
// 450.723 us; speedup vs baseline: 1.1674x; 1.1674x over previous
//
#include <hip/hip_runtime.h>

// Problem constants (B=2, N=1000, D=6, L=12, C=32, K=16, H=8)
#define NB 2
#define NN 1000
#define ND 6
#define NK 16
#define NH 8
#define DM 384        // L*C
#define MROWS 12000   // B*N*D
#define NTOK 2000     // B*N
#define NS 96         // K*D

static __device__ __forceinline__ float4 ld4(const float* p){ return *reinterpret_cast<const float4*>(p); }
static __device__ __forceinline__ void st4(float* p, float4 v){ *reinterpret_cast<float4*>(p) = v; }

#define SCALE 0.14433756729740646f   // 1/sqrt(48)
#define GELU_K 0.70710678118654752f  // 1/sqrt(2)

// ---------------------------------------------------------------------------
// Kernel 1: Qa/Ka/Va = x @ {Wq,Wk,Wv} + bias.   M=12000, N=384 (x3), K=384.
// 128x128 tile, BK=16, 256 threads, 8x8 micro-tile.  (unchanged from R1)
// ---------------------------------------------------------------------------
__global__ __launch_bounds__(256, 2)
void k_qkv(const float* __restrict__ x,
           const float* __restrict__ Wq, const float* __restrict__ bq,
           const float* __restrict__ Wk, const float* __restrict__ bk,
           const float* __restrict__ Wv, const float* __restrict__ bv,
           float* __restrict__ Qa, float* __restrict__ Ka, float* __restrict__ Va)
{
    __shared__ float As[16*132];   // transposed A tile [k][row]
    __shared__ float Bs[16*128];   // B tile [k][col]

    const int tid = threadIdx.x;
    const int tx = tid & 15, ty = tid >> 4;
    const int r0 = blockIdx.x * 128;
    const int wsel = blockIdx.y / 3;
    const int c0 = (blockIdx.y % 3) * 128;
    const float* W   = (wsel == 0) ? Wq : (wsel == 1) ? Wk : Wv;
    const float* bi  = (wsel == 0) ? bq : (wsel == 1) ? bk : bv;
    float*       out = (wsel == 0) ? Qa : (wsel == 1) ? Ka : Va;

    float acc[8][8];
    #pragma unroll
    for (int i = 0; i < 8; i++)
        #pragma unroll
        for (int j = 0; j < 8; j++) acc[i][j] = 0.f;

    const int lrow = tid >> 2;          // 0..63
    const int lkc  = (tid & 3) << 2;    // 0,4,8,12
    const int bkr  = tid >> 5;          // 0..7
    const int bcc  = (tid & 31) << 2;   // 0..124

    for (int k0 = 0; k0 < DM; k0 += 16) {
        #pragma unroll
        for (int hf = 0; hf < 2; hf++) {
            const int r = lrow + hf*64;
            const int gr = r0 + r;
            float4 v = make_float4(0.f, 0.f, 0.f, 0.f);
            if (gr < MROWS) v = ld4(&x[(size_t)gr*DM + k0 + lkc]);
            As[(lkc+0)*132 + r] = v.x;
            As[(lkc+1)*132 + r] = v.y;
            As[(lkc+2)*132 + r] = v.z;
            As[(lkc+3)*132 + r] = v.w;
        }
        #pragma unroll
        for (int hf = 0; hf < 2; hf++) {
            const int kr = bkr + hf*8;
            st4(&Bs[kr*128 + bcc], ld4(&W[(size_t)(k0+kr)*DM + c0 + bcc]));
        }
        __syncthreads();
        #pragma unroll
        for (int kk = 0; kk < 16; kk++) {
            const float4 a0 = ld4(&As[kk*132 + 4*ty]);
            const float4 a1 = ld4(&As[kk*132 + 64 + 4*ty]);
            const float4 b0 = ld4(&Bs[kk*128 + 4*tx]);
            const float4 b1 = ld4(&Bs[kk*128 + 64 + 4*tx]);
            const float a[8] = {a0.x,a0.y,a0.z,a0.w,a1.x,a1.y,a1.z,a1.w};
            const float b[8] = {b0.x,b0.y,b0.z,b0.w,b1.x,b1.y,b1.z,b1.w};
            #pragma unroll
            for (int i = 0; i < 8; i++)
                #pragma unroll
                for (int j = 0; j < 8; j++)
                    acc[i][j] = fmaf(a[i], b[j], acc[i][j]);
        }
        __syncthreads();
    }

    #pragma unroll
    for (int i = 0; i < 8; i++) {
        const int r = (i < 4) ? (4*ty + i) : (64 + 4*ty + i - 4);
        const int gr = r0 + r;
        if (gr >= MROWS) continue;
        #pragma unroll
        for (int jh = 0; jh < 2; jh++) {
            const int cl = jh ? (64 + 4*tx) : (4*tx);
            const int c = c0 + cl;
            const float4 bv = ld4(&bi[c]);
            float4 v;
            v.x = acc[i][4*jh+0] + bv.x;
            v.y = acc[i][4*jh+1] + bv.y;
            v.z = acc[i][4*jh+2] + bv.z;
            v.w = acc[i][4*jh+3] + bv.w;
            st4(&out[(size_t)gr*DM + c], v);
        }
    }
}

// ---------------------------------------------------------------------------
// Kernel 2 (REWRITTEN): attention per token, ALL 8 HEADS AT ONCE.
//   - stage full 1536B K rows in 6 chunks of 16 rows (each gathered row
//     touched exactly once, contiguous+coalesced)
//   - all 48 (h,l) score rows per chunk, 256 threads fully active
//   - single softmax pass over 48x96 scores
//   - 6 V chunks, ctx accumulated in registers (3 float4 / thread)
// LDS = 52.9 KB -> 3 blocks/CU. All hot LDS reads <=2-way conflict (free).
// ---------------------------------------------------------------------------
__global__ __launch_bounds__(256, 3)
void k_attn(float* __restrict__ Qa,           // in: Q rows; out: ctx (in-place)
            const float* __restrict__ Ka,
            const float* __restrict__ Va,
            const int* __restrict__ topk)
{
    __shared__ float Qs[6*384];     // full Q rows              9216 B
    __shared__ float Sm[48*98];     // scores (h*6+l) x 96 pad 18816 B
    __shared__ float Rs[16*388];    // chunk of 16 full rows   24832 B
    __shared__ int   idxs[NK];

    const int tid = threadIdx.x;
    const int bn  = blockIdx.x;                  // 0..1999
    const int bb  = (bn >= NN) ? NN : 0;         // b*1000
    const size_t qbase = (size_t)bn * (ND*DM);

    if (tid < NK) idxs[tid] = topk[bn*NK + tid];
    {   // stage full Q (2304 floats = 576 float4, contiguous)
        const float4* src = (const float4*)(Qa + qbase);
        float4* dst = (float4*)Qs;
        #pragma unroll
        for (int p = 0; p < 3; p++) {
            const int i = tid + p*256;
            if (i < 576) dst[i] = src[i];
        }
    }
    __syncthreads();

    const int s_l = tid & 15;             // score-phase s within chunk
    const int hh8 = (tid >> 4) & 7;       // score-phase head
    const int lh  = tid >> 7;             // score-phase l-half (0/1)

    // ================= scores: S[h][l][s] = Q[l][h.] . K[s][h.] * SCALE ====
    for (int c = 0; c < 6; ++c) {
        // stage 16 full K rows (1536 float4)
        #pragma unroll
        for (int p = 0; p < 6; p++) {
            const int p4 = tid + p*256;
            const int r16 = p4 / 96, c4 = p4 - r16*96;
            const int sg = c*16 + r16;
            const int k = sg / 6, d = sg - k*6;
            const float4 v = ld4(&Ka[((size_t)(bb + idxs[k])*ND + d)*DM + c4*4]);
            st4(&Rs[r16*388 + c4*4], v);
        }
        __syncthreads();
        {
            const float* Krow = &Rs[s_l*388 + hh8*48];
            const float* Q0 = &Qs[(lh*3+0)*384 + hh8*48];
            const float* Q1 = &Qs[(lh*3+1)*384 + hh8*48];
            const float* Q2 = &Qs[(lh*3+2)*384 + hh8*48];
            float a0 = 0.f, a1 = 0.f, a2 = 0.f;
            #pragma unroll
            for (int j = 0; j < 12; ++j) {
                const float4 kv = ld4(&Krow[4*j]);
                const float4 q0 = ld4(&Q0[4*j]);
                const float4 q1 = ld4(&Q1[4*j]);
                const float4 q2 = ld4(&Q2[4*j]);
                a0 = fmaf(kv.x,q0.x, fmaf(kv.y,q0.y, fmaf(kv.z,q0.z, fmaf(kv.w,q0.w, a0))));
                a1 = fmaf(kv.x,q1.x, fmaf(kv.y,q1.y, fmaf(kv.z,q1.z, fmaf(kv.w,q1.w, a1))));
                a2 = fmaf(kv.x,q2.x, fmaf(kv.y,q2.y, fmaf(kv.z,q2.z, fmaf(kv.w,q2.w, a2))));
            }
            const int sg = c*16 + s_l;
            Sm[(hh8*6 + lh*3 + 0)*98 + sg] = a0 * SCALE;
            Sm[(hh8*6 + lh*3 + 1)*98 + sg] = a1 * SCALE;
            Sm[(hh8*6 + lh*3 + 2)*98 + sg] = a2 * SCALE;
        }
        __syncthreads();
    }

    // ================= softmax over s (96) for the 48 (h,l) rows ==========
    {
        const int g = tid >> 2, l4 = tid & 3;      // 4-lane group per row
        if (g < 48) {
            float* row = &Sm[g*98];
            float m = -3.0e38f;
            #pragma unroll
            for (int i = 0; i < 24; ++i) m = fmaxf(m, row[l4 + 4*i]);
            m = fmaxf(m, __shfl_xor(m, 1));
            m = fmaxf(m, __shfl_xor(m, 2));
            float e[24];
            float sum = 0.f;
            #pragma unroll
            for (int i = 0; i < 24; ++i) { e[i] = __expf(row[l4 + 4*i] - m); sum += e[i]; }
            sum += __shfl_xor(sum, 1);
            sum += __shfl_xor(sum, 2);
            const float inv = 1.f / sum;
            #pragma unroll
            for (int i = 0; i < 24; ++i) row[l4 + 4*i] = e[i] * inv;
        }
    }
    __syncthreads();

    // ================= ctx = A @ V, ctx in registers ======================
    const int g  = tid >> 2;              // (h,l) group, active for tid<192
    const int jl = tid & 3;               // float4 lane within 48-col slice
    const int hh = g / 6, ll = g - hh*6;
    float4 acc0 = make_float4(0.f,0.f,0.f,0.f);
    float4 acc1 = make_float4(0.f,0.f,0.f,0.f);
    float4 acc2 = make_float4(0.f,0.f,0.f,0.f);

    for (int c = 0; c < 6; ++c) {
        // stage 16 full V rows
        #pragma unroll
        for (int p = 0; p < 6; p++) {
            const int p4 = tid + p*256;
            const int r16 = p4 / 96, c4 = p4 - r16*96;
            const int sg = c*16 + r16;
            const int k = sg / 6, d = sg - k*6;
            const float4 v = ld4(&Va[((size_t)(bb + idxs[k])*ND + d)*DM + c4*4]);
            st4(&Rs[r16*388 + c4*4], v);
        }
        __syncthreads();
        if (g < 48) {
            const float* arow = &Sm[g*98 + c*16];
            #pragma unroll
            for (int s = 0; s < 16; ++s) {
                const float a = arow[s];
                const float* vr = &Rs[s*388 + hh*48 + 4*jl];
                const float4 v0 = ld4(&vr[0]);
                const float4 v1 = ld4(&vr[16]);
                const float4 v2 = ld4(&vr[32]);
                acc0.x = fmaf(a, v0.x, acc0.x); acc0.y = fmaf(a, v0.y, acc0.y);
                acc0.z = fmaf(a, v0.z, acc0.z); acc0.w = fmaf(a, v0.w, acc0.w);
                acc1.x = fmaf(a, v1.x, acc1.x); acc1.y = fmaf(a, v1.y, acc1.y);
                acc1.z = fmaf(a, v1.z, acc1.z); acc1.w = fmaf(a, v1.w, acc1.w);
                acc2.x = fmaf(a, v2.x, acc2.x); acc2.y = fmaf(a, v2.y, acc2.y);
                acc2.z = fmaf(a, v2.z, acc2.z); acc2.w = fmaf(a, v2.w, acc2.w);
            }
        }
        __syncthreads();
    }

    if (g < 48) {   // write ctx over the Q slice
        float* dst = &Qa[qbase + (size_t)ll*DM + hh*48 + 4*jl];
        st4(&dst[0],  acc0);
        st4(&dst[16], acc1);
        st4(&dst[32], acc2);
    }
}

// ---------------------------------------------------------------------------
// Kernel 3: out = LN(x + ctx@Wo + bo); out += MLP(out).  (unchanged from R1)
// ---------------------------------------------------------------------------
__global__ __launch_bounds__(256, 2)
void k_out(const float* __restrict__ ctx, const float* __restrict__ x,
           const float* __restrict__ Wo, const float* __restrict__ bo,
           const float* __restrict__ ln_g, const float* __restrict__ ln_b,
           const float* __restrict__ W1, const float* __restrict__ b1,
           const float* __restrict__ W2, const float* __restrict__ b2,
           float* __restrict__ out)
{
    __shared__ float smem[8256];   // GEMM: As[16*68]@0, Bs[16*128]@1088 ; then hs[64*129]
    __shared__ float W1s[2048];    // [c][o] row-major (32x64)
    __shared__ float W2t[2048];    // transposed: [c][o] (32x64)
    __shared__ float b1s[64];
    __shared__ float cns[96];      // ln_g | ln_b | b2

    const int tid = threadIdx.x;
    const int tx = tid & 15, ty = tid >> 4;
    const int r0 = blockIdx.x * 64;
    const int c0 = blockIdx.y * 128;

    for (int p = tid; p < 2048; p += 256) {
        W1s[p] = W1[p];
        const int o = p >> 5, c = p & 31;   // W2 is [o][c]
        W2t[c*64 + o] = W2[p];
    }
    if (tid < 64) b1s[tid] = b1[tid];
    if (tid < 32) { cns[tid] = ln_g[tid]; cns[32+tid] = ln_b[tid]; cns[64+tid] = b2[tid]; }

    float* As = smem;            // [16][68] transposed
    float* Bs = smem + 1088;     // [16][128]

    float acc[4][8];
    #pragma unroll
    for (int i = 0; i < 4; i++)
        #pragma unroll
        for (int j = 0; j < 8; j++) acc[i][j] = 0.f;

    const int lrow = tid >> 2;          // 0..63
    const int lkc  = (tid & 3) << 2;
    const int bkr  = tid >> 5;
    const int bcc  = (tid & 31) << 2;

    for (int k0 = 0; k0 < DM; k0 += 16) {
        {
            const int gr = r0 + lrow;
            float4 v = make_float4(0.f, 0.f, 0.f, 0.f);
            if (gr < MROWS) v = ld4(&ctx[(size_t)gr*DM + k0 + lkc]);
            As[(lkc+0)*68 + lrow] = v.x;
            As[(lkc+1)*68 + lrow] = v.y;
            As[(lkc+2)*68 + lrow] = v.z;
            As[(lkc+3)*68 + lrow] = v.w;
        }
        #pragma unroll
        for (int hf = 0; hf < 2; hf++) {
            const int kr = bkr + hf*8;
            st4(&Bs[kr*128 + bcc], ld4(&Wo[(size_t)(k0+kr)*DM + c0 + bcc]));
        }
        __syncthreads();
        #pragma unroll
        for (int kk = 0; kk < 16; kk++) {
            const float4 a0 = ld4(&As[kk*68 + 4*ty]);
            const float4 b0 = ld4(&Bs[kk*128 + 4*tx]);
            const float4 b1v = ld4(&Bs[kk*128 + 64 + 4*tx]);
            const float a[4] = {a0.x,a0.y,a0.z,a0.w};
            const float b[8] = {b0.x,b0.y,b0.z,b0.w,b1v.x,b1v.y,b1v.z,b1v.w};
            #pragma unroll
            for (int i = 0; i < 4; i++)
                #pragma unroll
                for (int j = 0; j < 8; j++)
                    acc[i][j] = fmaf(a[i], b[j], acc[i][j]);
        }
        __syncthreads();
    }

    // epilogue: h = ctx@Wo + bo + x  -> hs (aliases As/Bs; safe after last sync)
    float* hs = smem;   // [64][129]
    #pragma unroll
    for (int i = 0; i < 4; i++) {
        const int r = 4*ty + i;
        const int gr = r0 + r;
        if (gr < MROWS) {
            #pragma unroll
            for (int jh = 0; jh < 2; jh++) {
                const int cl = jh ? (64 + 4*tx) : (4*tx);
                const int c = c0 + cl;
                const float4 xv = ld4(&x[(size_t)gr*DM + c]);
                const float4 bv = ld4(&bo[c]);
                hs[r*129 + cl + 0] = acc[i][4*jh+0] + bv.x + xv.x;
                hs[r*129 + cl + 1] = acc[i][4*jh+1] + bv.y + xv.y;
                hs[r*129 + cl + 2] = acc[i][4*jh+2] + bv.z + xv.z;
                hs[r*129 + cl + 3] = acc[i][4*jh+3] + bv.w + xv.w;
            }
        }
    }
    __syncthreads();

    // LN + MLP: thread -> (row = tid&63, group g = tid>>6); group = 32 cols
    {
        const int row = tid & 63, g = tid >> 6;
        const int gr = r0 + row;
        if (gr < MROWS) {
            const float* hrow = &hs[row*129 + g*32];
            float mu = 0.f;
            #pragma unroll
            for (int c = 0; c < 32; c++) mu += hrow[c];
            mu *= 0.03125f;
            float var = 0.f;
            #pragma unroll
            for (int c = 0; c < 32; c++) { const float d = hrow[c] - mu; var = fmaf(d, d, var); }
            var *= 0.03125f;
            const float rstd = 1.0f / sqrtf(var + 1e-5f);

            // layer1: y = fused @ W1 + b1   (y statically indexed)
            float y[64];
            #pragma unroll
            for (int o4 = 0; o4 < 16; o4++) {
                const float4 bv = ld4(&b1s[4*o4]);
                y[4*o4+0] = bv.x; y[4*o4+1] = bv.y; y[4*o4+2] = bv.z; y[4*o4+3] = bv.w;
            }
            for (int c = 0; c < 32; c++) {
                const float fc = (hrow[c] - mu) * rstd * cns[c] + cns[32 + c];
                const float4* w = (const float4*)&W1s[c*64];
                #pragma unroll
                for (int j = 0; j < 16; j++) {
                    const float4 wv = w[j];
                    y[4*j+0] = fmaf(fc, wv.x, y[4*j+0]);
                    y[4*j+1] = fmaf(fc, wv.y, y[4*j+1]);
                    y[4*j+2] = fmaf(fc, wv.z, y[4*j+2]);
                    y[4*j+3] = fmaf(fc, wv.w, y[4*j+3]);
                }
            }
            // exact GELU
            #pragma unroll
            for (int o = 0; o < 64; o++) {
                const float v = y[o];
                y[o] = 0.5f * v * (1.0f + erff(v * GELU_K));
            }
            // layer2 + final add:  out = fused + (gelu(y) @ W2 + b2)
            float* orow = &out[(size_t)gr*DM + c0 + g*32];
            for (int c = 0; c < 32; c++) {
                const float fc = (hrow[c] - mu) * rstd * cns[c] + cns[32 + c];
                float zc = cns[64 + c];
                const float4* w = (const float4*)&W2t[c*64];
                #pragma unroll
                for (int j = 0; j < 16; j++) {
                    const float4 wv = w[j];
                    zc = fmaf(y[4*j+0], wv.x, zc);
                    zc = fmaf(y[4*j+1], wv.y, zc);
                    zc = fmaf(y[4*j+2], wv.z, zc);
                    zc = fmaf(y[4*j+3], wv.w, zc);
                }
                orow[c] = fc + zc;
            }
        }
    }
}

// ---------------------------------------------------------------------------
extern "C" void kernel_launch(void* const* d_in, const int* in_sizes, int n_in,
                              void* d_out, int out_size, void* d_ws, size_t ws_size,
                              hipStream_t stream)
{
    const float* x   = (const float*)d_in[0];
    const int*   tk  = (const int*)  d_in[1];
    const float* Wq  = (const float*)d_in[2];
    const float* bq  = (const float*)d_in[3];
    const float* Wk  = (const float*)d_in[4];
    const float* bk  = (const float*)d_in[5];
    const float* Wv  = (const float*)d_in[6];
    const float* bv  = (const float*)d_in[7];
    const float* Wo  = (const float*)d_in[8];
    const float* bo  = (const float*)d_in[9];
    const float* lng = (const float*)d_in[10];
    const float* lnb = (const float*)d_in[11];
    const float* W1  = (const float*)d_in[12];
    const float* b1  = (const float*)d_in[13];
    const float* W2  = (const float*)d_in[14];
    const float* b2  = (const float*)d_in[15];
    float* out = (float*)d_out;

    // workspace: Qa (becomes ctx in-place), Ka, Va  — 3 * 12000*384 floats = 55.3 MB
    float* Qa = (float*)d_ws;
    float* Ka = Qa + (size_t)MROWS * DM;
    float* Va = Ka + (size_t)MROWS * DM;

    k_qkv<<<dim3(94, 9), 256, 0, stream>>>(x, Wq, bq, Wk, bk, Wv, bv, Qa, Ka, Va);
    k_attn<<<dim3(NTOK), 256, 0, stream>>>(Qa, Ka, Va, tk);
    k_out<<<dim3(188, 3), 256, 0, stream>>>(Qa, x, Wo, bo, lng, lnb, W1, b1, W2, b2, out);
}

// Round 3
// 391.323 us; speedup vs baseline: 1.3446x; 1.1518x over previous
//
#include <hip/hip_runtime.h>

// Problem constants (B=2, N=1000, D=6, L=12, C=32, K=16, H=8)
#define NB 2
#define NN 1000
#define ND 6
#define NK 16
#define NH 8
#define DM 384        // L*C
#define MROWS 12000   // B*N*D
#define NTOK 2000     // B*N
#define NS 96         // K*D

typedef unsigned short u16;
typedef __attribute__((ext_vector_type(8))) short bf16x8;   // 8 bf16 (4 VGPRs)
typedef __attribute__((ext_vector_type(4))) float f32x4;

static __device__ __forceinline__ float4 ld4(const float* p){ return *reinterpret_cast<const float4*>(p); }
static __device__ __forceinline__ void st4(float* p, float4 v){ *reinterpret_cast<float4*>(p) = v; }

#define SCALE 0.14433756729740646f   // 1/sqrt(48)
#define GELU_K 0.70710678118654752f  // 1/sqrt(2)

// bf16 round-to-nearest-even of fp32, as raw u16
static __device__ __forceinline__ u16 bf_hi(float a){
    unsigned u = __float_as_uint(a);
    unsigned r = u + 0x7fffu + ((u >> 16) & 1u);
    return (u16)(r >> 16);
}
static __device__ __forceinline__ void bf_split(float a, u16& h, u16& l){
    h = bf_hi(a);
    const float hf = __uint_as_float(((unsigned)h) << 16);
    l = bf_hi(a - hf);
}

// ---------------------------------------------------------------------------
// Kernel 0: convert x -> xh/xl (row-major bf16 hi/lo) and Wq/Wk/Wv ->
// transposed [n][k] bf16 hi/lo (so MFMA B-fragments are contiguous-k reads).
// ---------------------------------------------------------------------------
#define NX4 1152000   // x float4 chunks  (12000*384/4)
#define NW4 36864     // per-weight float4 chunks (384*384/4)
__global__ __launch_bounds__(256)
void k_convert(const float* __restrict__ x,
               const float* __restrict__ Wq, const float* __restrict__ Wk,
               const float* __restrict__ Wv,
               u16* __restrict__ xh, u16* __restrict__ xl,
               u16* __restrict__ Wth, u16* __restrict__ Wtl)
{
    const int idx = blockIdx.x * 256 + threadIdx.x;
    if (idx < NX4) {
        const float4 v = ld4(&x[(size_t)idx*4]);
        u16 h0,l0,h1,l1,h2,l2,h3,l3;
        bf_split(v.x,h0,l0); bf_split(v.y,h1,l1); bf_split(v.z,h2,l2); bf_split(v.w,h3,l3);
        ushort4 vh; vh.x=h0; vh.y=h1; vh.z=h2; vh.w=h3;
        ushort4 vl; vl.x=l0; vl.y=l1; vl.z=l2; vl.w=l3;
        *reinterpret_cast<ushort4*>(&xh[(size_t)idx*4]) = vh;
        *reinterpret_cast<ushort4*>(&xl[(size_t)idx*4]) = vl;
    } else if (idx < NX4 + 3*NW4) {
        int t = idx - NX4;
        const int w = t / NW4; t -= w*NW4;
        const float* W = (w==0) ? Wq : (w==1) ? Wk : Wv;
        const int k  = t / 96;              // source row (k index)
        const int n4 = (t - k*96) * 4;      // source col base (n index)
        const float4 v = ld4(&W[(size_t)k*DM + n4]);
        u16* oh = Wth + (size_t)w*DM*DM;
        u16* ol = Wtl + (size_t)w*DM*DM;
        u16 h,l;
        bf_split(v.x,h,l); oh[(size_t)(n4+0)*DM + k] = h; ol[(size_t)(n4+0)*DM + k] = l;
        bf_split(v.y,h,l); oh[(size_t)(n4+1)*DM + k] = h; ol[(size_t)(n4+1)*DM + k] = l;
        bf_split(v.z,h,l); oh[(size_t)(n4+2)*DM + k] = h; ol[(size_t)(n4+2)*DM + k] = l;
        bf_split(v.w,h,l); oh[(size_t)(n4+3)*DM + k] = h; ol[(size_t)(n4+3)*DM + k] = l;
    }
}

// ---------------------------------------------------------------------------
// Kernel 1 (MFMA): Qa/Ka/Va = x @ {Wq,Wk,Wv} + bias via bf16 hi/lo 3-MFMA.
// 128x128 tile, BK=64, 4 waves each computing 64x64 (4x4 frags of 16x16x32).
// LDS layout [kgrp][row][8] -> both staging writes and frag reads bank-balanced.
// ---------------------------------------------------------------------------
__global__ __launch_bounds__(256, 2)
void k_qkvm(const u16* __restrict__ xh, const u16* __restrict__ xl,
            const u16* __restrict__ Wth, const u16* __restrict__ Wtl,
            const float* __restrict__ bq, const float* __restrict__ bk,
            const float* __restrict__ bv,
            float* __restrict__ Qa, float* __restrict__ Ka, float* __restrict__ Va)
{
    __shared__ u16 Ash[2][8192];   // [hi/lo][kgrp*1024 + row*8 + j]
    __shared__ u16 Bsh[2][8192];

    const int tid = threadIdx.x;
    const int r0 = blockIdx.x * 128;
    const int wsel = blockIdx.y / 3;
    const int c0 = (blockIdx.y % 3) * 128;
    const u16* Wh = Wth + (size_t)wsel * DM * DM;
    const u16* Wl = Wtl + (size_t)wsel * DM * DM;

    const int lane = tid & 63, wid = tid >> 6;
    const int wm = wid >> 1, wn = wid & 1;       // wave -> 64x64 quadrant
    const int fr = lane & 15, fg = lane >> 4;    // frag row/col + k-group

    f32x4 acc[4][4];
    #pragma unroll
    for (int i = 0; i < 4; i++)
        #pragma unroll
        for (int j = 0; j < 4; j++) acc[i][j] = (f32x4){0.f,0.f,0.f,0.f};

    const int srow = tid >> 3;      // 0..31 (+p*32)
    const int skc  = tid & 7;       // k-chunk of 8

    for (int k0 = 0; k0 < DM; k0 += 64) {
        __syncthreads();
        #pragma unroll
        for (int p = 0; p < 4; ++p) {
            const int row = srow + p*32;
            const int lo = skc*1024 + row*8;
            // A tile (x rows)
            const int gr = r0 + row;
            uint4 vh = make_uint4(0u,0u,0u,0u), vl = vh;
            if (gr < MROWS) {
                const size_t ga = (size_t)gr*DM + k0 + skc*8;
                vh = *reinterpret_cast<const uint4*>(&xh[ga]);
                vl = *reinterpret_cast<const uint4*>(&xl[ga]);
            }
            *reinterpret_cast<uint4*>(&Ash[0][lo]) = vh;
            *reinterpret_cast<uint4*>(&Ash[1][lo]) = vl;
            // B tile (Wt rows = output cols)
            const size_t gb = (size_t)(c0 + row)*DM + k0 + skc*8;
            *reinterpret_cast<uint4*>(&Bsh[0][lo]) = *reinterpret_cast<const uint4*>(&Wh[gb]);
            *reinterpret_cast<uint4*>(&Bsh[1][lo]) = *reinterpret_cast<const uint4*>(&Wl[gb]);
        }
        __syncthreads();
        #pragma unroll
        for (int ks = 0; ks < 2; ++ks) {
            const int kb = (ks*4 + fg) * 1024;
            bf16x8 ah[4], al[4], bh[4], blo[4];
            #pragma unroll
            for (int t = 0; t < 4; ++t) {
                const int ro = kb + (wm*64 + t*16 + fr)*8;
                ah[t] = *reinterpret_cast<const bf16x8*>(&Ash[0][ro]);
                al[t] = *reinterpret_cast<const bf16x8*>(&Ash[1][ro]);
                const int co = kb + (wn*64 + t*16 + fr)*8;
                bh[t]  = *reinterpret_cast<const bf16x8*>(&Bsh[0][co]);
                blo[t] = *reinterpret_cast<const bf16x8*>(&Bsh[1][co]);
            }
            #pragma unroll
            for (int mt = 0; mt < 4; ++mt)
                #pragma unroll
                for (int nt = 0; nt < 4; ++nt) {
                    acc[mt][nt] = __builtin_amdgcn_mfma_f32_16x16x32_bf16(ah[mt], bh[nt],  acc[mt][nt], 0,0,0);
                    acc[mt][nt] = __builtin_amdgcn_mfma_f32_16x16x32_bf16(al[mt], bh[nt],  acc[mt][nt], 0,0,0);
                    acc[mt][nt] = __builtin_amdgcn_mfma_f32_16x16x32_bf16(ah[mt], blo[nt], acc[mt][nt], 0,0,0);
                }
        }
    }

    const float* bias = (wsel==0) ? bq : (wsel==1) ? bk : bv;
    float*       outp = (wsel==0) ? Qa : (wsel==1) ? Ka : Va;
    #pragma unroll
    for (int mt = 0; mt < 4; ++mt) {
        const int rbase = r0 + wm*64 + mt*16 + fg*4;
        #pragma unroll
        for (int nt = 0; nt < 4; ++nt) {
            const int col = c0 + wn*64 + nt*16 + fr;
            const float bb_ = bias[col];
            #pragma unroll
            for (int i = 0; i < 4; ++i) {
                const int rr = rbase + i;
                if (rr < MROWS) outp[(size_t)rr*DM + col] = acc[mt][nt][i] + bb_;
            }
        }
    }
}

// ---------------------------------------------------------------------------
// Kernel 2: attention per token, all 8 heads at once. (unchanged from R2)
// ---------------------------------------------------------------------------
__global__ __launch_bounds__(256, 3)
void k_attn(float* __restrict__ Qa,           // in: Q rows; out: ctx (in-place)
            const float* __restrict__ Ka,
            const float* __restrict__ Va,
            const int* __restrict__ topk)
{
    __shared__ float Qs[6*384];
    __shared__ float Sm[48*98];
    __shared__ float Rs[16*388];
    __shared__ int   idxs[NK];

    const int tid = threadIdx.x;
    const int bn  = blockIdx.x;
    const int bb  = (bn >= NN) ? NN : 0;
    const size_t qbase = (size_t)bn * (ND*DM);

    if (tid < NK) idxs[tid] = topk[bn*NK + tid];
    {
        const float4* src = (const float4*)(Qa + qbase);
        float4* dst = (float4*)Qs;
        #pragma unroll
        for (int p = 0; p < 3; p++) {
            const int i = tid + p*256;
            if (i < 576) dst[i] = src[i];
        }
    }
    __syncthreads();

    const int s_l = tid & 15;
    const int hh8 = (tid >> 4) & 7;
    const int lh  = tid >> 7;

    for (int c = 0; c < 6; ++c) {
        #pragma unroll
        for (int p = 0; p < 6; p++) {
            const int p4 = tid + p*256;
            const int r16 = p4 / 96, c4 = p4 - r16*96;
            const int sg = c*16 + r16;
            const int k = sg / 6, d = sg - k*6;
            const float4 v = ld4(&Ka[((size_t)(bb + idxs[k])*ND + d)*DM + c4*4]);
            st4(&Rs[r16*388 + c4*4], v);
        }
        __syncthreads();
        {
            const float* Krow = &Rs[s_l*388 + hh8*48];
            const float* Q0 = &Qs[(lh*3+0)*384 + hh8*48];
            const float* Q1 = &Qs[(lh*3+1)*384 + hh8*48];
            const float* Q2 = &Qs[(lh*3+2)*384 + hh8*48];
            float a0 = 0.f, a1 = 0.f, a2 = 0.f;
            #pragma unroll
            for (int j = 0; j < 12; ++j) {
                const float4 kv = ld4(&Krow[4*j]);
                const float4 q0 = ld4(&Q0[4*j]);
                const float4 q1 = ld4(&Q1[4*j]);
                const float4 q2 = ld4(&Q2[4*j]);
                a0 = fmaf(kv.x,q0.x, fmaf(kv.y,q0.y, fmaf(kv.z,q0.z, fmaf(kv.w,q0.w, a0))));
                a1 = fmaf(kv.x,q1.x, fmaf(kv.y,q1.y, fmaf(kv.z,q1.z, fmaf(kv.w,q1.w, a1))));
                a2 = fmaf(kv.x,q2.x, fmaf(kv.y,q2.y, fmaf(kv.z,q2.z, fmaf(kv.w,q2.w, a2))));
            }
            const int sg = c*16 + s_l;
            Sm[(hh8*6 + lh*3 + 0)*98 + sg] = a0 * SCALE;
            Sm[(hh8*6 + lh*3 + 1)*98 + sg] = a1 * SCALE;
            Sm[(hh8*6 + lh*3 + 2)*98 + sg] = a2 * SCALE;
        }
        __syncthreads();
    }

    {
        const int g = tid >> 2, l4 = tid & 3;
        if (g < 48) {
            float* row = &Sm[g*98];
            float m = -3.0e38f;
            #pragma unroll
            for (int i = 0; i < 24; ++i) m = fmaxf(m, row[l4 + 4*i]);
            m = fmaxf(m, __shfl_xor(m, 1));
            m = fmaxf(m, __shfl_xor(m, 2));
            float e[24];
            float sum = 0.f;
            #pragma unroll
            for (int i = 0; i < 24; ++i) { e[i] = __expf(row[l4 + 4*i] - m); sum += e[i]; }
            sum += __shfl_xor(sum, 1);
            sum += __shfl_xor(sum, 2);
            const float inv = 1.f / sum;
            #pragma unroll
            for (int i = 0; i < 24; ++i) row[l4 + 4*i] = e[i] * inv;
        }
    }
    __syncthreads();

    const int g  = tid >> 2;
    const int jl = tid & 3;
    const int hh = g / 6, ll = g - hh*6;
    float4 acc0 = make_float4(0.f,0.f,0.f,0.f);
    float4 acc1 = make_float4(0.f,0.f,0.f,0.f);
    float4 acc2 = make_float4(0.f,0.f,0.f,0.f);

    for (int c = 0; c < 6; ++c) {
        #pragma unroll
        for (int p = 0; p < 6; p++) {
            const int p4 = tid + p*256;
            const int r16 = p4 / 96, c4 = p4 - r16*96;
            const int sg = c*16 + r16;
            const int k = sg / 6, d = sg - k*6;
            const float4 v = ld4(&Va[((size_t)(bb + idxs[k])*ND + d)*DM + c4*4]);
            st4(&Rs[r16*388 + c4*4], v);
        }
        __syncthreads();
        if (g < 48) {
            const float* arow = &Sm[g*98 + c*16];
            #pragma unroll
            for (int s = 0; s < 16; ++s) {
                const float a = arow[s];
                const float* vr = &Rs[s*388 + hh*48 + 4*jl];
                const float4 v0 = ld4(&vr[0]);
                const float4 v1 = ld4(&vr[16]);
                const float4 v2 = ld4(&vr[32]);
                acc0.x = fmaf(a, v0.x, acc0.x); acc0.y = fmaf(a, v0.y, acc0.y);
                acc0.z = fmaf(a, v0.z, acc0.z); acc0.w = fmaf(a, v0.w, acc0.w);
                acc1.x = fmaf(a, v1.x, acc1.x); acc1.y = fmaf(a, v1.y, acc1.y);
                acc1.z = fmaf(a, v1.z, acc1.z); acc1.w = fmaf(a, v1.w, acc1.w);
                acc2.x = fmaf(a, v2.x, acc2.x); acc2.y = fmaf(a, v2.y, acc2.y);
                acc2.z = fmaf(a, v2.z, acc2.z); acc2.w = fmaf(a, v2.w, acc2.w);
            }
        }
        __syncthreads();
    }

    if (g < 48) {
        float* dst = &Qa[qbase + (size_t)ll*DM + hh*48 + 4*jl];
        st4(&dst[0],  acc0);
        st4(&dst[16], acc1);
        st4(&dst[32], acc2);
    }
}

// ---------------------------------------------------------------------------
// Kernel 3: out = LN(x + ctx@Wo + bo); out += MLP(out).  (unchanged from R2)
// ---------------------------------------------------------------------------
__global__ __launch_bounds__(256, 2)
void k_out(const float* __restrict__ ctx, const float* __restrict__ x,
           const float* __restrict__ Wo, const float* __restrict__ bo,
           const float* __restrict__ ln_g, const float* __restrict__ ln_b,
           const float* __restrict__ W1, const float* __restrict__ b1,
           const float* __restrict__ W2, const float* __restrict__ b2,
           float* __restrict__ out)
{
    __shared__ float smem[8256];
    __shared__ float W1s[2048];
    __shared__ float W2t[2048];
    __shared__ float b1s[64];
    __shared__ float cns[96];

    const int tid = threadIdx.x;
    const int tx = tid & 15, ty = tid >> 4;
    const int r0 = blockIdx.x * 64;
    const int c0 = blockIdx.y * 128;

    for (int p = tid; p < 2048; p += 256) {
        W1s[p] = W1[p];
        const int o = p >> 5, c = p & 31;
        W2t[c*64 + o] = W2[p];
    }
    if (tid < 64) b1s[tid] = b1[tid];
    if (tid < 32) { cns[tid] = ln_g[tid]; cns[32+tid] = ln_b[tid]; cns[64+tid] = b2[tid]; }

    float* As = smem;
    float* Bs = smem + 1088;

    float acc[4][8];
    #pragma unroll
    for (int i = 0; i < 4; i++)
        #pragma unroll
        for (int j = 0; j < 8; j++) acc[i][j] = 0.f;

    const int lrow = tid >> 2;
    const int lkc  = (tid & 3) << 2;
    const int bkr  = tid >> 5;
    const int bcc  = (tid & 31) << 2;

    for (int k0 = 0; k0 < DM; k0 += 16) {
        {
            const int gr = r0 + lrow;
            float4 v = make_float4(0.f, 0.f, 0.f, 0.f);
            if (gr < MROWS) v = ld4(&ctx[(size_t)gr*DM + k0 + lkc]);
            As[(lkc+0)*68 + lrow] = v.x;
            As[(lkc+1)*68 + lrow] = v.y;
            As[(lkc+2)*68 + lrow] = v.z;
            As[(lkc+3)*68 + lrow] = v.w;
        }
        #pragma unroll
        for (int hf = 0; hf < 2; hf++) {
            const int kr = bkr + hf*8;
            st4(&Bs[kr*128 + bcc], ld4(&Wo[(size_t)(k0+kr)*DM + c0 + bcc]));
        }
        __syncthreads();
        #pragma unroll
        for (int kk = 0; kk < 16; kk++) {
            const float4 a0 = ld4(&As[kk*68 + 4*ty]);
            const float4 b0 = ld4(&Bs[kk*128 + 4*tx]);
            const float4 b1v = ld4(&Bs[kk*128 + 64 + 4*tx]);
            const float a[4] = {a0.x,a0.y,a0.z,a0.w};
            const float b[8] = {b0.x,b0.y,b0.z,b0.w,b1v.x,b1v.y,b1v.z,b1v.w};
            #pragma unroll
            for (int i = 0; i < 4; i++)
                #pragma unroll
                for (int j = 0; j < 8; j++)
                    acc[i][j] = fmaf(a[i], b[j], acc[i][j]);
        }
        __syncthreads();
    }

    float* hs = smem;
    #pragma unroll
    for (int i = 0; i < 4; i++) {
        const int r = 4*ty + i;
        const int gr = r0 + r;
        if (gr < MROWS) {
            #pragma unroll
            for (int jh = 0; jh < 2; jh++) {
                const int cl = jh ? (64 + 4*tx) : (4*tx);
                const int c = c0 + cl;
                const float4 xv = ld4(&x[(size_t)gr*DM + c]);
                const float4 bv = ld4(&bo[c]);
                hs[r*129 + cl + 0] = acc[i][4*jh+0] + bv.x + xv.x;
                hs[r*129 + cl + 1] = acc[i][4*jh+1] + bv.y + xv.y;
                hs[r*129 + cl + 2] = acc[i][4*jh+2] + bv.z + xv.z;
                hs[r*129 + cl + 3] = acc[i][4*jh+3] + bv.w + xv.w;
            }
        }
    }
    __syncthreads();

    {
        const int row = tid & 63, g = tid >> 6;
        const int gr = r0 + row;
        if (gr < MROWS) {
            const float* hrow = &hs[row*129 + g*32];
            float mu = 0.f;
            #pragma unroll
            for (int c = 0; c < 32; c++) mu += hrow[c];
            mu *= 0.03125f;
            float var = 0.f;
            #pragma unroll
            for (int c = 0; c < 32; c++) { const float d = hrow[c] - mu; var = fmaf(d, d, var); }
            var *= 0.03125f;
            const float rstd = 1.0f / sqrtf(var + 1e-5f);

            float y[64];
            #pragma unroll
            for (int o4 = 0; o4 < 16; o4++) {
                const float4 bv = ld4(&b1s[4*o4]);
                y[4*o4+0] = bv.x; y[4*o4+1] = bv.y; y[4*o4+2] = bv.z; y[4*o4+3] = bv.w;
            }
            for (int c = 0; c < 32; c++) {
                const float fc = (hrow[c] - mu) * rstd * cns[c] + cns[32 + c];
                const float4* w = (const float4*)&W1s[c*64];
                #pragma unroll
                for (int j = 0; j < 16; j++) {
                    const float4 wv = w[j];
                    y[4*j+0] = fmaf(fc, wv.x, y[4*j+0]);
                    y[4*j+1] = fmaf(fc, wv.y, y[4*j+1]);
                    y[4*j+2] = fmaf(fc, wv.z, y[4*j+2]);
                    y[4*j+3] = fmaf(fc, wv.w, y[4*j+3]);
                }
            }
            #pragma unroll
            for (int o = 0; o < 64; o++) {
                const float v = y[o];
                y[o] = 0.5f * v * (1.0f + erff(v * GELU_K));
            }
            float* orow = &out[(size_t)gr*DM + c0 + g*32];
            for (int c = 0; c < 32; c++) {
                const float fc = (hrow[c] - mu) * rstd * cns[c] + cns[32 + c];
                float zc = cns[64 + c];
                const float4* w = (const float4*)&W2t[c*64];
                #pragma unroll
                for (int j = 0; j < 16; j++) {
                    const float4 wv = w[j];
                    zc = fmaf(y[4*j+0], wv.x, zc);
                    zc = fmaf(y[4*j+1], wv.y, zc);
                    zc = fmaf(y[4*j+2], wv.z, zc);
                    zc = fmaf(y[4*j+3], wv.w, zc);
                }
                orow[c] = fc + zc;
            }
        }
    }
}

// ---------------------------------------------------------------------------
extern "C" void kernel_launch(void* const* d_in, const int* in_sizes, int n_in,
                              void* d_out, int out_size, void* d_ws, size_t ws_size,
                              hipStream_t stream)
{
    const float* x   = (const float*)d_in[0];
    const int*   tk  = (const int*)  d_in[1];
    const float* Wq  = (const float*)d_in[2];
    const float* bq  = (const float*)d_in[3];
    const float* Wk  = (const float*)d_in[4];
    const float* bk  = (const float*)d_in[5];
    const float* Wv  = (const float*)d_in[6];
    const float* bv  = (const float*)d_in[7];
    const float* Wo  = (const float*)d_in[8];
    const float* bo  = (const float*)d_in[9];
    const float* lng = (const float*)d_in[10];
    const float* lnb = (const float*)d_in[11];
    const float* W1  = (const float*)d_in[12];
    const float* b1  = (const float*)d_in[13];
    const float* W2  = (const float*)d_in[14];
    const float* b2  = (const float*)d_in[15];
    float* out = (float*)d_out;

    // workspace layout (75.5 MB total):
    //   Qa/Ka/Va fp32 (55.3 MB) | xh/xl bf16 (18.4 MB) | Wth/Wtl bf16 (1.8 MB)
    float* Qa = (float*)d_ws;
    float* Ka = Qa + (size_t)MROWS * DM;
    float* Va = Ka + (size_t)MROWS * DM;
    u16* xh  = (u16*)(Va + (size_t)MROWS * DM);
    u16* xl  = xh + (size_t)MROWS * DM;
    u16* Wth = xl + (size_t)MROWS * DM;
    u16* Wtl = Wth + (size_t)3 * DM * DM;

    k_convert<<<dim3(4932), 256, 0, stream>>>(x, Wq, Wk, Wv, xh, xl, Wth, Wtl);
    k_qkvm<<<dim3(94, 9), 256, 0, stream>>>(xh, xl, Wth, Wtl, bq, bk, bv, Qa, Ka, Va);
    k_attn<<<dim3(NTOK), 256, 0, stream>>>(Qa, Ka, Va, tk);
    k_out<<<dim3(188, 3), 256, 0, stream>>>(Qa, x, Wo, bo, lng, lnb, W1, b1, W2, b2, out);
}